// Round 4
// baseline (230.070 us; speedup 1.0000x reference)
//
#include <hip/hip_runtime.h>

// BiasedCrossAttention B=2, LQ=LK=1024, D=1024, H=16, DH=64. fp32 in/out.
// R4: barrier-free attention K-loop — K/V/Q MFMA fragments loaded DIRECTLY from
//     global (S^T/O^T layouts make them contiguous half8), per-wave P LDS,
//     in-block split-K (2-way) for occupancy, single merge barrier.
// ws (halves, 32 MB): q16|k16|v16 (2M ea) | Qh|Kh|Vt (2M ea) | W16 (4x1M).

typedef _Float16 half8 __attribute__((ext_vector_type(8)));
typedef _Float16 half4_t __attribute__((ext_vector_type(4)));
typedef float f32x4 __attribute__((ext_vector_type(4)));

#define MFMA16(a, b, c) __builtin_amdgcn_mfma_f32_16x16x32_f16((a), (b), (c), 0, 0, 0)

__device__ __forceinline__ void gload16(const void* g, void* l) {
  __builtin_amdgcn_global_load_lds(
      (const __attribute__((address_space(1))) unsigned int*)g,
      (__attribute__((address_space(3))) unsigned int*)l, 16, 0, 0);
}

// Rows of 64 halves (8 x 16B chunks), physical chunk = logical ^ (row & 7).
__device__ __forceinline__ half8 frag_ld(const _Float16* t, int row, int ck) {
  return *(const half8*)(t + row * 64 + (((ck ^ (row & 7)) << 3)));
}

// ------------------------------------------------- cvt fp32->fp16 (acts + weights)
__global__ __launch_bounds__(256) void cvt_f32_f16(
    const float* __restrict__ q, const float* __restrict__ k, const float* __restrict__ v,
    const float* __restrict__ Wq, const float* __restrict__ Wk,
    const float* __restrict__ Wv, const float* __restrict__ Wo,
    _Float16* __restrict__ q16, _Float16* __restrict__ k16, _Float16* __restrict__ v16,
    _Float16* __restrict__ w16) {
  const int y = blockIdx.y;
  if (y >= 3 && blockIdx.x >= 512) return;  // weights are 1M elems (512 blocks)
  const float* s;
  _Float16* d;
  const size_t M = (size_t)1024 * 1024;
  switch (y) {
    case 0: s = q;  d = q16; break;
    case 1: s = k;  d = k16; break;
    case 2: s = v;  d = v16; break;
    case 3: s = Wq; d = w16; break;
    case 4: s = Wk; d = w16 + M; break;
    case 5: s = Wv; d = w16 + 2 * M; break;
    default: s = Wo; d = w16 + 3 * M; break;
  }
  const size_t i = ((size_t)blockIdx.x * 256 + threadIdx.x) * 8;
  const float4 a = *(const float4*)(s + i);
  const float4 bvv = *(const float4*)(s + i + 4);
  half8 h;
  h[0] = (_Float16)a.x; h[1] = (_Float16)a.y; h[2] = (_Float16)a.z; h[3] = (_Float16)a.w;
  h[4] = (_Float16)bvv.x; h[5] = (_Float16)bvv.y; h[6] = (_Float16)bvv.z; h[7] = (_Float16)bvv.w;
  *(half8*)(d + i) = h;
}

// ------------------------------------------------- GEMM C = X @ W^T + bias (all fp16 in)
// 128x128 tile, BK=64, 4 waves x (64x64). Both operands via global_load_lds.
__global__ __launch_bounds__(256) void mm_bt(
    const _Float16* __restrict__ Aq, const _Float16* __restrict__ Ak,
    const _Float16* __restrict__ Av, const _Float16* __restrict__ W16,
    const float* __restrict__ c0, const float* __restrict__ c1,
    const float* __restrict__ c2, _Float16* __restrict__ Dq,
    _Float16* __restrict__ Dk, _Float16* __restrict__ Dvt,
    float* __restrict__ Df, int is_final) {
  __shared__ __align__(16) _Float16 lds[17408];  // As(8192) | Bs(8192); reused as Ct[128][136]
  _Float16* As = lds;
  _Float16* Bs = lds + 8192;

  const int tid = threadIdx.x;
  const int wv = tid >> 6, ln = tid & 63;
  const int quad = ln >> 4, col = ln & 15;
  const int wm = wv >> 1, wn = wv & 1;
  const int n0 = blockIdx.x * 128;
  const int m0 = blockIdx.y * 128;
  const int z = blockIdx.z;

  const _Float16* A = (z == 0) ? Aq : (z == 1) ? Ak : Av;
  const _Float16* Bw = W16 + (size_t)z * 1024 * 1024;
  const float* bias = (z == 0) ? c0 : (z == 1) ? c1 : c2;

  const f32x4 zero4 = {0.f, 0.f, 0.f, 0.f};
  f32x4 acc[4][4];
#pragma unroll
  for (int i = 0; i < 4; ++i)
#pragma unroll
    for (int j = 0; j < 4; ++j) acc[i][j] = zero4;

  for (int k0 = 0; k0 < 1024; k0 += 64) {
    __syncthreads();
#pragma unroll
    for (int j = 0; j < 4; ++j) {
      const int ci = j * 256 + wv * 64 + ln;
      const int row = ci >> 3;
      const int lc = (ci & 7) ^ (row & 7);
      gload16(A + (size_t)(m0 + row) * 1024 + k0 + lc * 8,
              As + (size_t)(j * 256 + wv * 64) * 8);
      gload16(Bw + (size_t)(n0 + row) * 1024 + k0 + lc * 8,
              Bs + (size_t)(j * 256 + wv * 64) * 8);
    }
    __syncthreads();
#pragma unroll
    for (int kk = 0; kk < 2; ++kk) {
      half8 af[4], bf[4];
#pragma unroll
      for (int mi = 0; mi < 4; ++mi)
        af[mi] = frag_ld(As, wm * 64 + mi * 16 + col, kk * 4 + quad);
#pragma unroll
      for (int ni = 0; ni < 4; ++ni)
        bf[ni] = frag_ld(Bs, wn * 64 + ni * 16 + col, kk * 4 + quad);
#pragma unroll
      for (int mi = 0; mi < 4; ++mi)
#pragma unroll
        for (int ni = 0; ni < 4; ++ni)
          acc[mi][ni] = MFMA16(af[mi], bf[ni], acc[mi][ni]);
    }
  }

  float bv[4];
#pragma unroll
  for (int ni = 0; ni < 4; ++ni) bv[ni] = bias[n0 + wn * 64 + ni * 16 + col];

  if (is_final) {
#pragma unroll
    for (int mi = 0; mi < 4; ++mi) {
      const int m_g = m0 + wm * 64 + mi * 16 + quad * 4;
#pragma unroll
      for (int ni = 0; ni < 4; ++ni) {
        const int n_g = n0 + wn * 64 + ni * 16 + col;
#pragma unroll
        for (int r = 0; r < 4; ++r)
          Df[(size_t)(m_g + r) * 1024 + n_g] = acc[mi][ni][r] + bv[ni];
      }
    }
  } else if (z < 2) {
    _Float16* D = z ? Dk : Dq;
#pragma unroll
    for (int mi = 0; mi < 4; ++mi) {
      const int m_g = m0 + wm * 64 + mi * 16 + quad * 4;
#pragma unroll
      for (int ni = 0; ni < 4; ++ni) {
        const int n_g = n0 + wn * 64 + ni * 16 + col;
        const int h = n_g >> 6, dh = n_g & 63;
#pragma unroll
        for (int r = 0; r < 4; ++r) {
          const int b = (m_g + r) >> 10, l = (m_g + r) & 1023;
          D[((size_t)((b * 16 + h) * 1024) + l) * 64 + dh] =
              (_Float16)(acc[mi][ni][r] + bv[ni]);
        }
      }
    }
  } else {
    // transpose through LDS -> Vt[bh][dh][l]
    __syncthreads();
    _Float16* Ct = lds;  // [128][136]
#pragma unroll
    for (int mi = 0; mi < 4; ++mi) {
      const int ml = wm * 64 + mi * 16 + quad * 4;
#pragma unroll
      for (int ni = 0; ni < 4; ++ni) {
        const int nl = wn * 64 + ni * 16 + col;
#pragma unroll
        for (int r = 0; r < 4; ++r)
          Ct[(size_t)nl * 136 + ml + r] = (_Float16)(acc[mi][ni][r] + bv[ni]);
      }
    }
    __syncthreads();
#pragma unroll
    for (int it = 0; it < 8; ++it) {
      const int ci = it * 256 + tid;
      const int n = ci >> 4;
      const int mc = (ci & 15) * 8;
      const half8 hv = *(const half8*)(Ct + (size_t)n * 136 + mc);
      const int n_g = n0 + n;
      const int h = n_g >> 6, dh = n_g & 63;
      const int m_g = m0 + mc;
      const int b = m_g >> 10, l = m_g & 1023;
      *(half8*)(Dvt + ((size_t)((b * 16 + h) * 64 + dh)) * 1024 + l) = hv;
    }
  }
}

// ------------------------------------------------- flash attention, barrier-free K-loop
// grid (LQ/32, B*H), 4 waves. wave = (khalf = wv>>1, qsub = wv&1).
// Wave handles 16 q-rows (q0 + qsub*16), keys [khalf*512, +512) in 8 iters of 64.
// S^T = K Q^T (A=K frags direct from Kh), O^T = V^T P^T (A=V frags direct from Vt).
// P^T through per-wave LDS (in-wave ordering, no barrier). One barrier to merge
// the two key-halves' online-softmax partials.
__global__ __launch_bounds__(256, 3) void attn(
    const _Float16* __restrict__ Qh, const _Float16* __restrict__ Kh,
    const _Float16* __restrict__ Vt, const float* __restrict__ biasL,
    const int* __restrict__ kpm, _Float16* __restrict__ AO) {
  __shared__ __align__(16) _Float16 Pt[4 * 1024];     // per-wave 16q x 64k, swizzled
  __shared__ __align__(16) float OxS[2 * 4 * 64 * 4]; // [qsub][ni][lane][4]
  __shared__ float MlS[2 * 2 * 64];                   // [qsub][{m,l}][lane]

  const int tid = threadIdx.x;
  const int wv = tid >> 6, ln = tid & 63;
  const int quad = ln >> 4, col = ln & 15;
  const int qsub = wv & 1, khalf = wv >> 1;
  const int q0 = blockIdx.x * 32;
  const int bh = blockIdx.y;
  const int b = bh >> 4, hh = bh & 15;
  const int qg = q0 + qsub * 16 + col;  // this lane's softmax row

  // Q fragments (B-operand) directly from global: contiguous half8
  const _Float16* Qp = Qh + ((size_t)bh * 1024 + qg) * 64;
  const half8 bq0 = *(const half8*)(Qp + quad * 8);
  const half8 bq1 = *(const half8*)(Qp + 32 + quad * 8);

  const f32x4 zero4 = {0.f, 0.f, 0.f, 0.f};
  f32x4 o[4];
#pragma unroll
  for (int ni = 0; ni < 4; ++ni) o[ni] = zero4;
  float m_i = -1e30f, l_i = 0.f;

  _Float16* Pw = Pt + wv * 1024;
  const _Float16* Kb = Kh + (size_t)bh * 1024 * 64;
  const _Float16* Vb = Vt + (size_t)bh * 64 * 1024;
  const float* biasRow = biasL + ((size_t)(b * 1024 + qg)) * 1024;
  const int* kpmRow = kpm + b * 1024;

  for (int it = 0; it < 8; ++it) {
    const int koff = khalf * 512 + it * 64;

    // S^T = K Q^T : s[mi][r] = S[koff+mi*16+quad*4+r][qg]
    f32x4 s[4];
#pragma unroll
    for (int mi = 0; mi < 4; ++mi) {
      const _Float16* Kp = Kb + (size_t)(koff + mi * 16 + col) * 64;
      f32x4 a4 = zero4;
      a4 = MFMA16(*(const half8*)(Kp + quad * 8), bq0, a4);
      a4 = MFMA16(*(const half8*)(Kp + 32 + quad * 8), bq1, a4);
      s[mi] = a4;
    }

    // bias + mask (vectorized, 4 consecutive keys per reg)
#pragma unroll
    for (int mi = 0; mi < 4; ++mi) {
      const int kg = koff + mi * 16 + quad * 4;
      const int4 mk4 = *(const int4*)&kpmRow[kg];
      const f32x4 bb = *(const f32x4*)&biasRow[kg];
      const int* mp = (const int*)&mk4;
#pragma unroll
      for (int r = 0; r < 4; ++r)
        s[mi][r] = mp[r] ? -1e9f : s[mi][r] * 0.125f + bb[r];
    }

    // per-lane online softmax (row = qg), 2 cross-quad shuffles per reduction
    float rm = -1e30f;
#pragma unroll
    for (int mi = 0; mi < 4; ++mi)
#pragma unroll
      for (int r = 0; r < 4; ++r) rm = fmaxf(rm, s[mi][r]);
    rm = fmaxf(rm, __shfl_xor(rm, 16));
    rm = fmaxf(rm, __shfl_xor(rm, 32));
    const float mn = fmaxf(m_i, rm);
    const float alpha = __expf(m_i - mn);
    m_i = mn;
    float ps = 0.f;
#pragma unroll
    for (int mi = 0; mi < 4; ++mi)
#pragma unroll
      for (int r = 0; r < 4; ++r) {
        const float p = __expf(s[mi][r] - mn);
        s[mi][r] = p;
        ps += p;
      }
    ps += __shfl_xor(ps, 16);
    ps += __shfl_xor(ps, 32);
    l_i = l_i * alpha + ps;
#pragma unroll
    for (int ni = 0; ni < 4; ++ni)
#pragma unroll
      for (int r = 0; r < 4; ++r) o[ni][r] *= alpha;

    // P^T -> per-wave LDS (row=q=col, 64 keys, swizzled); in-wave only, no barrier
#pragma unroll
    for (int mi = 0; mi < 4; ++mi) {
      half4_t h;
      h[0] = (_Float16)s[mi][0]; h[1] = (_Float16)s[mi][1];
      h[2] = (_Float16)s[mi][2]; h[3] = (_Float16)s[mi][3];
      const int kloc = mi * 16 + quad * 4;
      const int chunk = kloc >> 3;
      *(half4_t*)(Pw + col * 64 + (((chunk ^ (col & 7)) << 3) | (kloc & 7))) = h;
    }
    const half8 p0 = frag_ld(Pw, col, quad);
    const half8 p1 = frag_ld(Pw, col, 4 + quad);

    // O^T += V^T P^T (A=V frags direct from Vt: contiguous in k)
#pragma unroll
    for (int ni = 0; ni < 4; ++ni) {
      const _Float16* Vp = Vb + (size_t)(ni * 16 + col) * 1024 + koff;
      o[ni] = MFMA16(*(const half8*)(Vp + quad * 8), p0, o[ni]);
      o[ni] = MFMA16(*(const half8*)(Vp + 32 + quad * 8), p1, o[ni]);
    }
  }

  // merge the two key-halves (partner waves share qsub)
  if (khalf == 1) {
#pragma unroll
    for (int ni = 0; ni < 4; ++ni)
      *(f32x4*)&OxS[((qsub * 4 + ni) * 64 + ln) * 4] = o[ni];
    MlS[qsub * 128 + ln] = m_i;
    MlS[qsub * 128 + 64 + ln] = l_i;
  }
  __syncthreads();
  if (khalf == 0) {
    const float m2 = MlS[qsub * 128 + ln];
    const float l2 = MlS[qsub * 128 + 64 + ln];
    const float ms = fmaxf(m_i, m2);
    const float w1 = __expf(m_i - ms);
    const float w2 = __expf(m2 - ms);
    const float inv = 1.0f / (l_i * w1 + l2 * w2);
#pragma unroll
    for (int ni = 0; ni < 4; ++ni) {
      const f32x4 o2 = *(const f32x4*)&OxS[((qsub * 4 + ni) * 64 + ln) * 4];
      half4_t h;
#pragma unroll
      for (int r = 0; r < 4; ++r)
        h[r] = (_Float16)((o[ni][r] * w1 + o2[r] * w2) * inv);
      *(half4_t*)&AO[((size_t)(b * 1024 + qg)) * 1024 + hh * 64 + ni * 16 + quad * 4] = h;
    }
  }
}

extern "C" void kernel_launch(void* const* d_in, const int* in_sizes, int n_in,
                              void* d_out, int out_size, void* d_ws, size_t ws_size,
                              hipStream_t stream) {
  (void)in_sizes; (void)n_in; (void)out_size; (void)ws_size;
  const float* q = (const float*)d_in[0];
  const float* k = (const float*)d_in[1];
  const float* v = (const float*)d_in[2];
  const float* Wq = (const float*)d_in[3];
  const float* bq = (const float*)d_in[4];
  const float* Wk = (const float*)d_in[5];
  const float* bk = (const float*)d_in[6];
  const float* Wv = (const float*)d_in[7];
  const float* bv = (const float*)d_in[8];
  const float* Wo = (const float*)d_in[9];
  const float* bo = (const float*)d_in[10];
  const float* lb = (const float*)d_in[11];
  const int* kpm = (const int*)d_in[12];
  float* out = (float*)d_out;

  const size_t NT = (size_t)2 * 1024 * 1024;
  _Float16* q16 = (_Float16*)d_ws;
  _Float16* k16 = q16 + NT;
  _Float16* v16 = k16 + NT;
  _Float16* Qh = v16 + NT;
  _Float16* Kh = Qh + NT;
  _Float16* Vt = Kh + NT;
  _Float16* w16 = Vt + NT;  // 4 x 1M halves (Wq,Wk,Wv,Wo)
  _Float16* AO = q16;       // q16 dead after projections

  cvt_f32_f16<<<dim3(1024, 7), 256, 0, stream>>>(q, k, v, Wq, Wk, Wv, Wo,
                                                 q16, k16, v16, w16);
  mm_bt<<<dim3(8, 16, 3), 256, 0, stream>>>(q16, k16, v16, w16, bq, bk, bv,
                                            Qh, Kh, Vt, nullptr, 0);
  attn<<<dim3(32, 32), 256, 0, stream>>>(Qh, Kh, Vt, lb, kpm, AO);
  mm_bt<<<dim3(8, 16, 1), 256, 0, stream>>>(AO, nullptr, nullptr, w16 + 3 * NT / 2,
                                            bo, nullptr, nullptr, nullptr, nullptr,
                                            nullptr, out, 1);
}

// Round 5
// 186.145 us; speedup vs baseline: 1.2360x; 1.2360x over previous
//
#include <hip/hip_runtime.h>

// BiasedCrossAttention B=2, LQ=LK=1024, D=1024, H=16, DH=64. fp32 in/out.
// R5: grid-starvation fix. attn: 1024 blocks (32q x 2-way split-K) with async
//     LDS staging (R3's verified pattern, R4's verified math). GEMMs: 64x64
//     tiles -> 1536/512 blocks (was 384/128).
// ws (halves, 32 MB): q16|k16|v16 (2M ea) | Qh|Kh|Vt (2M ea) | W16 (4x1M).

typedef _Float16 half8 __attribute__((ext_vector_type(8)));
typedef _Float16 half4_t __attribute__((ext_vector_type(4)));
typedef float f32x4 __attribute__((ext_vector_type(4)));

#define MFMA16(a, b, c) __builtin_amdgcn_mfma_f32_16x16x32_f16((a), (b), (c), 0, 0, 0)

__device__ __forceinline__ void gload16(const void* g, void* l) {
  __builtin_amdgcn_global_load_lds(
      (const __attribute__((address_space(1))) unsigned int*)g,
      (__attribute__((address_space(3))) unsigned int*)l, 16, 0, 0);
}

// Rows of 64 halves (8 x 16B chunks), physical chunk = logical ^ (row & 7).
__device__ __forceinline__ half8 frag_ld(const _Float16* t, int row, int ck) {
  return *(const half8*)(t + row * 64 + (((ck ^ (row & 7)) << 3)));
}

// ------------------------------------------------- cvt fp32->fp16 (acts + weights)
__global__ __launch_bounds__(256) void cvt_f32_f16(
    const float* __restrict__ q, const float* __restrict__ k, const float* __restrict__ v,
    const float* __restrict__ Wq, const float* __restrict__ Wk,
    const float* __restrict__ Wv, const float* __restrict__ Wo,
    _Float16* __restrict__ q16, _Float16* __restrict__ k16, _Float16* __restrict__ v16,
    _Float16* __restrict__ w16) {
  const int y = blockIdx.y;
  if (y >= 3 && blockIdx.x >= 512) return;  // weights are 1M elems (512 blocks)
  const float* s;
  _Float16* d;
  const size_t M = (size_t)1024 * 1024;
  switch (y) {
    case 0: s = q;  d = q16; break;
    case 1: s = k;  d = k16; break;
    case 2: s = v;  d = v16; break;
    case 3: s = Wq; d = w16; break;
    case 4: s = Wk; d = w16 + M; break;
    case 5: s = Wv; d = w16 + 2 * M; break;
    default: s = Wo; d = w16 + 3 * M; break;
  }
  const size_t i = ((size_t)blockIdx.x * 256 + threadIdx.x) * 8;
  const float4 a = *(const float4*)(s + i);
  const float4 bvv = *(const float4*)(s + i + 4);
  half8 h;
  h[0] = (_Float16)a.x; h[1] = (_Float16)a.y; h[2] = (_Float16)a.z; h[3] = (_Float16)a.w;
  h[4] = (_Float16)bvv.x; h[5] = (_Float16)bvv.y; h[6] = (_Float16)bvv.z; h[7] = (_Float16)bvv.w;
  *(half8*)(d + i) = h;
}

// ------------------------------------------------- GEMM C = X @ W^T + bias, 64x64 tile
// BK=64, 4 waves in 2x2, each wave 32x32 (2x2 MFMA tiles). Both operands async-staged.
// Epilogues: is_final -> fp32 row-major; z<2 -> split-head fp16; z==2 -> Vt transpose.
__global__ __launch_bounds__(256) void mm64(
    const _Float16* __restrict__ Aq, const _Float16* __restrict__ Ak,
    const _Float16* __restrict__ Av, const _Float16* __restrict__ W16,
    const float* __restrict__ c0, const float* __restrict__ c1,
    const float* __restrict__ c2, _Float16* __restrict__ Dq,
    _Float16* __restrict__ Dk, _Float16* __restrict__ Dvt,
    float* __restrict__ Df, int is_final) {
  __shared__ __align__(16) _Float16 lds[8192];  // As(4096) | Bs(4096); reused as Ct[64][80]
  _Float16* As = lds;
  _Float16* Bs = lds + 4096;

  const int tid = threadIdx.x;
  const int wv = tid >> 6, ln = tid & 63;
  const int quad = ln >> 4, col = ln & 15;
  const int wm = wv >> 1, wn = wv & 1;
  const int n0 = blockIdx.x * 64;
  const int m0 = blockIdx.y * 64;
  const int z = blockIdx.z;

  const _Float16* A = (z == 0) ? Aq : (z == 1) ? Ak : Av;
  const _Float16* Bw = W16 + (size_t)z * 1024 * 1024;
  const float* bias = (z == 0) ? c0 : (z == 1) ? c1 : c2;

  const f32x4 zero4 = {0.f, 0.f, 0.f, 0.f};
  f32x4 acc[2][2];
#pragma unroll
  for (int i = 0; i < 2; ++i)
#pragma unroll
    for (int j = 0; j < 2; ++j) acc[i][j] = zero4;

  for (int k0 = 0; k0 < 1024; k0 += 64) {
    __syncthreads();
#pragma unroll
    for (int j = 0; j < 2; ++j) {
      const int ci = j * 256 + wv * 64 + ln;
      const int row = ci >> 3;
      const int lc = (ci & 7) ^ (row & 7);
      gload16(A + (size_t)(m0 + row) * 1024 + k0 + lc * 8,
              As + (size_t)(j * 256 + wv * 64) * 8);
      gload16(Bw + (size_t)(n0 + row) * 1024 + k0 + lc * 8,
              Bs + (size_t)(j * 256 + wv * 64) * 8);
    }
    __syncthreads();
#pragma unroll
    for (int kk = 0; kk < 2; ++kk) {
      half8 af[2], bf[2];
#pragma unroll
      for (int mi = 0; mi < 2; ++mi)
        af[mi] = frag_ld(As, wm * 32 + mi * 16 + col, kk * 4 + quad);
#pragma unroll
      for (int ni = 0; ni < 2; ++ni)
        bf[ni] = frag_ld(Bs, wn * 32 + ni * 16 + col, kk * 4 + quad);
#pragma unroll
      for (int mi = 0; mi < 2; ++mi)
#pragma unroll
        for (int ni = 0; ni < 2; ++ni)
          acc[mi][ni] = MFMA16(af[mi], bf[ni], acc[mi][ni]);
    }
  }

  float bv[2];
#pragma unroll
  for (int ni = 0; ni < 2; ++ni) bv[ni] = bias[n0 + wn * 32 + ni * 16 + col];

  if (is_final) {
#pragma unroll
    for (int mi = 0; mi < 2; ++mi) {
      const int m_g = m0 + wm * 32 + mi * 16 + quad * 4;
#pragma unroll
      for (int ni = 0; ni < 2; ++ni) {
        const int n_g = n0 + wn * 32 + ni * 16 + col;
#pragma unroll
        for (int r = 0; r < 4; ++r)
          Df[(size_t)(m_g + r) * 1024 + n_g] = acc[mi][ni][r] + bv[ni];
      }
    }
  } else if (z < 2) {
    _Float16* D = z ? Dk : Dq;
    const int h = n0 >> 6;
#pragma unroll
    for (int mi = 0; mi < 2; ++mi) {
      const int m_g = m0 + wm * 32 + mi * 16 + quad * 4;
#pragma unroll
      for (int ni = 0; ni < 2; ++ni) {
        const int dh = (wn * 32 + ni * 16 + col);
#pragma unroll
        for (int r = 0; r < 4; ++r) {
          const int b = (m_g + r) >> 10, l = (m_g + r) & 1023;
          D[((size_t)((b * 16 + h) * 1024) + l) * 64 + dh] =
              (_Float16)(acc[mi][ni][r] + bv[ni]);
        }
      }
    }
  } else {
    // transpose 64x64 through LDS -> Vt[bh][dh][l]
    __syncthreads();
    _Float16* Ct = lds;  // [64][80] (stride 80 halves = 160B, keeps 16B alignment)
#pragma unroll
    for (int mi = 0; mi < 2; ++mi) {
      const int ml = wm * 32 + mi * 16 + quad * 4;
#pragma unroll
      for (int ni = 0; ni < 2; ++ni) {
        const int nl = wn * 32 + ni * 16 + col;
#pragma unroll
        for (int r = 0; r < 4; ++r)
          Ct[(size_t)nl * 80 + ml + r] = (_Float16)(acc[mi][ni][r] + bv[ni]);
      }
    }
    __syncthreads();
    const int h = n0 >> 6;
#pragma unroll
    for (int it = 0; it < 2; ++it) {
      const int ci = it * 256 + tid;
      const int n = ci >> 3;          // dh-local 0..63
      const int mc = (ci & 7) * 8;    // l-local chunk
      const half8 hv = *(const half8*)(Ct + (size_t)n * 80 + mc);
      const int m_g = m0 + mc;
      const int b = m_g >> 10, l = m_g & 1023;
      *(half8*)(Dvt + ((size_t)((b * 16 + h) * 64 + n)) * 1024 + l) = hv;
    }
  }
}

// ------------------------------------------------- flash attention
// grid (LQ/32, B*H), 4 waves: wave = (khalf=wv>>1, qsub=wv&1); 16 q-rows x 512 keys.
// Per iter each wave async-stages one 8KB tile (K-h0/K-h1/V-h0/V-h1); S^T/O^T MFMA
// from swizzled LDS frags; per-lane online softmax; per-wave P LDS; split-K merge.
__global__ __launch_bounds__(256) void attn(
    const _Float16* __restrict__ Qh, const _Float16* __restrict__ Kh,
    const _Float16* __restrict__ Vt, const float* __restrict__ biasL,
    const int* __restrict__ kpm, _Float16* __restrict__ AO) {
  __shared__ __align__(16) _Float16 KV[4][4096];  // K_h0 | K_h1 | V_h0 | V_h1 (swizzled)
  __shared__ __align__(16) _Float16 Pt[4][1024];  // per-wave P; reused as f32x4 Ox[512]

  const int tid = threadIdx.x;
  const int wv = tid >> 6, ln = tid & 63;
  const int quad = ln >> 4, col = ln & 15;
  const int qsub = wv & 1, khalf = wv >> 1;
  const int q0 = blockIdx.x * 32;
  const int bh = blockIdx.y;
  const int b = bh >> 4, hh = bh & 15;
  const int qg = q0 + qsub * 16 + col;  // this lane's softmax row

  // Q fragments (B-operand) direct from global: contiguous half8, loaded once
  const _Float16* Qp = Qh + ((size_t)bh * 1024 + qg) * 64;
  const half8 bq0 = *(const half8*)(Qp + quad * 8);
  const half8 bq1 = *(const half8*)(Qp + 32 + quad * 8);

  const f32x4 zero4 = {0.f, 0.f, 0.f, 0.f};
  f32x4 o[4];
#pragma unroll
  for (int ni = 0; ni < 4; ++ni) o[ni] = zero4;
  float m_i = -1e30f, l_i = 0.f;

  _Float16* Pw = Pt[wv];
  const _Float16* Ks = KV[khalf];
  const _Float16* Vs = KV[2 + khalf];
  const float* biasRow = biasL + ((size_t)(b * 1024 + qg)) * 1024;
  const int* kpmRow = kpm + b * 1024;

  // staging source for MY wave's tile (wave wv stages tile wv)
  const int stage_koff_base = (wv & 1) * 512;  // tiles 0,2 -> h0; 1,3 -> h1

  for (int it = 0; it < 8; ++it) {
    const int koff = khalf * 512 + it * 64;
    const int skoff = stage_koff_base + it * 64;

    __syncthreads();
    // wave wv stages tile wv (8 x 1KB async issues)
#pragma unroll
    for (int j = 0; j < 8; ++j) {
      const int ci = j * 64 + ln;
      const int row = ci >> 3;
      const int lc = (ci & 7) ^ (row & 7);
      const void* src =
          (wv < 2) ? (const void*)(Kh + ((size_t)bh * 1024 + skoff + row) * 64 + lc * 8)
                   : (const void*)(Vt + ((size_t)bh * 64 + row) * 1024 + skoff + lc * 8);
      gload16(src, KV[wv] + j * 512);
    }
    // bias + mask direct from global (overlaps DMA)
    f32x4 bb[4];
    int4 mk4[4];
#pragma unroll
    for (int mi = 0; mi < 4; ++mi) {
      const int kg = koff + mi * 16 + quad * 4;
      mk4[mi] = *(const int4*)&kpmRow[kg];
      bb[mi] = *(const f32x4*)&biasRow[kg];
    }
    __syncthreads();

    // S^T = K Q^T : s[mi][r] = S[koff+mi*16+quad*4+r][qg]
    f32x4 s[4];
#pragma unroll
    for (int mi = 0; mi < 4; ++mi) {
      f32x4 a4 = zero4;
      a4 = MFMA16(frag_ld(Ks, mi * 16 + col, quad), bq0, a4);
      a4 = MFMA16(frag_ld(Ks, mi * 16 + col, 4 + quad), bq1, a4);
      s[mi] = a4;
    }
#pragma unroll
    for (int mi = 0; mi < 4; ++mi) {
      const int* mp = (const int*)&mk4[mi];
#pragma unroll
      for (int r = 0; r < 4; ++r)
        s[mi][r] = mp[r] ? -1e9f : s[mi][r] * 0.125f + bb[mi][r];
    }

    // per-lane online softmax (row = qg), 2 cross-quad shuffles per reduction
    float rm = -1e30f;
#pragma unroll
    for (int mi = 0; mi < 4; ++mi)
#pragma unroll
      for (int r = 0; r < 4; ++r) rm = fmaxf(rm, s[mi][r]);
    rm = fmaxf(rm, __shfl_xor(rm, 16));
    rm = fmaxf(rm, __shfl_xor(rm, 32));
    const float mn = fmaxf(m_i, rm);
    const float alpha = __expf(m_i - mn);
    m_i = mn;
    float ps = 0.f;
#pragma unroll
    for (int mi = 0; mi < 4; ++mi)
#pragma unroll
      for (int r = 0; r < 4; ++r) {
        const float p = __expf(s[mi][r] - mn);
        s[mi][r] = p;
        ps += p;
      }
    ps += __shfl_xor(ps, 16);
    ps += __shfl_xor(ps, 32);
    l_i = l_i * alpha + ps;
#pragma unroll
    for (int ni = 0; ni < 4; ++ni)
#pragma unroll
      for (int r = 0; r < 4; ++r) o[ni][r] *= alpha;

    // P^T -> per-wave LDS (in-wave ordering only)
#pragma unroll
    for (int mi = 0; mi < 4; ++mi) {
      half4_t h;
      h[0] = (_Float16)s[mi][0]; h[1] = (_Float16)s[mi][1];
      h[2] = (_Float16)s[mi][2]; h[3] = (_Float16)s[mi][3];
      const int kloc = mi * 16 + quad * 4;
      const int chunk = kloc >> 3;
      *(half4_t*)(Pw + col * 64 + (((chunk ^ (col & 7)) << 3) | (kloc & 7))) = h;
    }
    const half8 p0 = frag_ld(Pw, col, quad);
    const half8 p1 = frag_ld(Pw, col, 4 + quad);

    // O^T += V^T P^T
#pragma unroll
    for (int ni = 0; ni < 4; ++ni) {
      o[ni] = MFMA16(frag_ld(Vs, ni * 16 + col, quad), p0, o[ni]);
      o[ni] = MFMA16(frag_ld(Vs, ni * 16 + col, 4 + quad), p1, o[ni]);
    }
  }

  // split-K merge: khalf==1 publishes partials via LDS (aliased), khalf==0 merges
  __syncthreads();
  f32x4* Ox = (f32x4*)&Pt[0][0];       // 512 x 16B = 8KB (P dead)
  float* MlS = (float*)&KV[0][0];      // 256 floats (KV dead)
  if (khalf == 1) {
#pragma unroll
    for (int ni = 0; ni < 4; ++ni) Ox[(qsub * 4 + ni) * 64 + ln] = o[ni];
    MlS[qsub * 64 + ln] = m_i;
    MlS[128 + qsub * 64 + ln] = l_i;
  }
  __syncthreads();
  if (khalf == 0) {
    const float m2 = MlS[qsub * 64 + ln];
    const float l2 = MlS[128 + qsub * 64 + ln];
    const float ms = fmaxf(m_i, m2);
    const float w1 = __expf(m_i - ms);
    const float w2 = __expf(m2 - ms);
    const float inv = 1.0f / (l_i * w1 + l2 * w2);
#pragma unroll
    for (int ni = 0; ni < 4; ++ni) {
      const f32x4 o2 = Ox[(qsub * 4 + ni) * 64 + ln];
      half4_t h;
#pragma unroll
      for (int r = 0; r < 4; ++r)
        h[r] = (_Float16)((o[ni][r] * w1 + o2[r] * w2) * inv);
      *(half4_t*)&AO[((size_t)(b * 1024 + qg)) * 1024 + hh * 64 + ni * 16 + quad * 4] = h;
    }
  }
}

extern "C" void kernel_launch(void* const* d_in, const int* in_sizes, int n_in,
                              void* d_out, int out_size, void* d_ws, size_t ws_size,
                              hipStream_t stream) {
  (void)in_sizes; (void)n_in; (void)out_size; (void)ws_size;
  const float* q = (const float*)d_in[0];
  const float* k = (const float*)d_in[1];
  const float* v = (const float*)d_in[2];
  const float* Wq = (const float*)d_in[3];
  const float* bq = (const float*)d_in[4];
  const float* Wk = (const float*)d_in[5];
  const float* bk = (const float*)d_in[6];
  const float* Wv = (const float*)d_in[7];
  const float* bv = (const float*)d_in[8];
  const float* Wo = (const float*)d_in[9];
  const float* bo = (const float*)d_in[10];
  const float* lb = (const float*)d_in[11];
  const int* kpm = (const int*)d_in[12];
  float* out = (float*)d_out;

  const size_t NT = (size_t)2 * 1024 * 1024;
  _Float16* q16 = (_Float16*)d_ws;
  _Float16* k16 = q16 + NT;
  _Float16* v16 = k16 + NT;
  _Float16* Qh = v16 + NT;
  _Float16* Kh = Qh + NT;
  _Float16* Vt = Kh + NT;
  _Float16* w16 = Vt + NT;  // 4 x 1M halves (Wq,Wk,Wv,Wo)
  _Float16* AO = q16;       // q16 dead after projections

  cvt_f32_f16<<<dim3(1024, 7), 256, 0, stream>>>(q, k, v, Wq, Wk, Wv, Wo,
                                                 q16, k16, v16, w16);
  mm64<<<dim3(16, 32, 3), 256, 0, stream>>>(q16, k16, v16, w16, bq, bk, bv,
                                            Qh, Kh, Vt, nullptr, 0);
  attn<<<dim3(32, 32), 256, 0, stream>>>(Qh, Kh, Vt, lb, kpm, AO);
  mm64<<<dim3(16, 32, 1), 256, 0, stream>>>(AO, nullptr, nullptr, w16 + 3 * NT / 2,
                                            bo, nullptr, nullptr, nullptr, nullptr,
                                            nullptr, out, 1);
}

// Round 6
// 180.329 us; speedup vs baseline: 1.2758x; 1.0322x over previous
//
#include <hip/hip_runtime.h>

// BiasedCrossAttention B=2, LQ=LK=1024, D=1024, H=16, DH=64. fp32 in/out.
// R6: software-pipelined K-loops. Raw s_barrier + explicit s_waitcnt vmcnt(N)
//     (never 0 mid-loop) so global_load_lds prefetch stays in flight across
//     barriers — removes the per-iteration vmcnt(0) drain that capped R2-R5
//     at ~130 TF (GEMM) / 47 us (attn).
// ws (halves, 32 MB): q16|k16|v16 (2M ea) | Qh|Kh|Vt (2M ea) | W16 (4x1M).

typedef _Float16 half8 __attribute__((ext_vector_type(8)));
typedef _Float16 half4_t __attribute__((ext_vector_type(4)));
typedef float f32x4 __attribute__((ext_vector_type(4)));

#define MFMA16(a, b, c) __builtin_amdgcn_mfma_f32_16x16x32_f16((a), (b), (c), 0, 0, 0)

#define WAITCNT_VM(n) asm volatile("s_waitcnt vmcnt(" #n ")" ::: "memory")
#define WAITCNT_LGKM0() asm volatile("s_waitcnt lgkmcnt(0)" ::: "memory")
#define RAW_BARRIER() asm volatile("s_barrier" ::: "memory")

__device__ __forceinline__ void gload16(const void* g, void* l) {
  __builtin_amdgcn_global_load_lds(
      (const __attribute__((address_space(1))) unsigned int*)g,
      (__attribute__((address_space(3))) unsigned int*)l, 16, 0, 0);
}

// Rows of 64 halves (8 x 16B chunks), physical chunk = logical ^ (row & 7).
__device__ __forceinline__ half8 frag_ld(const _Float16* t, int row, int ck) {
  return *(const half8*)(t + row * 64 + (((ck ^ (row & 7)) << 3)));
}

// ------------------------------------------------- cvt fp32->fp16 (acts + weights)
__global__ __launch_bounds__(256) void cvt_f32_f16(
    const float* __restrict__ q, const float* __restrict__ k, const float* __restrict__ v,
    const float* __restrict__ Wq, const float* __restrict__ Wk,
    const float* __restrict__ Wv, const float* __restrict__ Wo,
    _Float16* __restrict__ q16, _Float16* __restrict__ k16, _Float16* __restrict__ v16,
    _Float16* __restrict__ w16) {
  const int y = blockIdx.y;
  if (y >= 3 && blockIdx.x >= 512) return;  // weights are 1M elems (512 blocks)
  const float* s;
  _Float16* d;
  const size_t M = (size_t)1024 * 1024;
  switch (y) {
    case 0: s = q;  d = q16; break;
    case 1: s = k;  d = k16; break;
    case 2: s = v;  d = v16; break;
    case 3: s = Wq; d = w16; break;
    case 4: s = Wk; d = w16 + M; break;
    case 5: s = Wv; d = w16 + 2 * M; break;
    default: s = Wo; d = w16 + 3 * M; break;
  }
  const size_t i = ((size_t)blockIdx.x * 256 + threadIdx.x) * 8;
  const float4 a = *(const float4*)(s + i);
  const float4 bvv = *(const float4*)(s + i + 4);
  half8 h;
  h[0] = (_Float16)a.x; h[1] = (_Float16)a.y; h[2] = (_Float16)a.z; h[3] = (_Float16)a.w;
  h[4] = (_Float16)bvv.x; h[5] = (_Float16)bvv.y; h[6] = (_Float16)bvv.z; h[7] = (_Float16)bvv.w;
  *(half8*)(d + i) = h;
}

// ------------------------------------------------- pipelined GEMM C = X @ W^T + bias
// BM=64, BN=128, BK=64, 4 waves (2x2): wave tile 32x64 (2x4 MFMA tiles).
// Double-buffered LDS (48 KB = 3 blocks/CU); per-iter vmcnt(6) gate (6 DMA/thread).
__global__ __launch_bounds__(256) void mmp(
    const _Float16* __restrict__ Aq, const _Float16* __restrict__ Ak,
    const _Float16* __restrict__ Av, const _Float16* __restrict__ W16,
    const float* __restrict__ c0, const float* __restrict__ c1,
    const float* __restrict__ c2, _Float16* __restrict__ Dq,
    _Float16* __restrict__ Dk, _Float16* __restrict__ Dvt,
    float* __restrict__ Df, int is_final) {
  __shared__ __align__(16) _Float16 lds[24576];  // 2 x (A 4096 | B 8192); z==2 reuse Ct[128][72]

  const int tid = threadIdx.x;
  const int wv = tid >> 6, ln = tid & 63;
  const int quad = ln >> 4, col = ln & 15;
  const int wm = wv >> 1, wn = wv & 1;
  const int n0 = blockIdx.x * 128;
  const int m0 = blockIdx.y * 64;
  const int z = blockIdx.z;

  const _Float16* A = (z == 0) ? Aq : (z == 1) ? Ak : Av;
  const _Float16* Bw = W16 + (size_t)z * 1024 * 1024;
  const float* bias = (z == 0) ? c0 : (z == 1) ? c1 : c2;

  // stage tile k0 into buffer buf: chunks 0..511 = A (64 rows), 512..1535 = B (128 rows)
  auto stage = [&](int buf, int k0) {
#pragma unroll
    for (int j = 0; j < 6; ++j) {
      const int ci = j * 256 + tid;
      const _Float16* src;
      if (ci < 512) {
        const int row = ci >> 3, lc = (ci & 7) ^ (row & 7);
        src = A + (size_t)(m0 + row) * 1024 + k0 + lc * 8;
      } else {
        const int di = ci - 512;
        const int row = di >> 3, lc = (di & 7) ^ (row & 7);
        src = Bw + (size_t)(n0 + row) * 1024 + k0 + lc * 8;
      }
      gload16(src, lds + buf * 12288 + (j * 256 + wv * 64) * 8);  // A at +0, B at +4096
    }
  };

  const f32x4 zero4 = {0.f, 0.f, 0.f, 0.f};
  f32x4 acc[2][4];
#pragma unroll
  for (int i = 0; i < 2; ++i)
#pragma unroll
    for (int j = 0; j < 4; ++j) acc[i][j] = zero4;

  stage(0, 0);
  for (int i = 0; i < 15; ++i) {
    stage((i + 1) & 1, (i + 1) * 64);
    WAITCNT_VM(6);   // tile i landed (for this wave); prefetch i+1 stays in flight
    RAW_BARRIER();   // tile i landed for all waves
    const _Float16* As = lds + (i & 1) * 12288;
    const _Float16* Bs = As + 4096;
    half8 af[2][2], bf[2][4];
#pragma unroll
    for (int kk = 0; kk < 2; ++kk) {
#pragma unroll
      for (int mi = 0; mi < 2; ++mi)
        af[kk][mi] = frag_ld(As, wm * 32 + mi * 16 + col, kk * 4 + quad);
#pragma unroll
      for (int ni = 0; ni < 4; ++ni)
        bf[kk][ni] = frag_ld(Bs, wn * 64 + ni * 16 + col, kk * 4 + quad);
    }
    WAITCNT_LGKM0();
    RAW_BARRIER();   // all waves done reading buf (i&1) -> safe to DMA over next iter
#pragma unroll
    for (int kk = 0; kk < 2; ++kk)
#pragma unroll
      for (int mi = 0; mi < 2; ++mi)
#pragma unroll
        for (int ni = 0; ni < 4; ++ni)
          acc[mi][ni] = MFMA16(af[kk][mi], bf[kk][ni], acc[mi][ni]);
  }
  {  // last tile (15), buffer 1; no further staging
    WAITCNT_VM(0);
    RAW_BARRIER();
    const _Float16* As = lds + 12288;
    const _Float16* Bs = As + 4096;
#pragma unroll
    for (int kk = 0; kk < 2; ++kk) {
      half8 af[2], bf[4];
#pragma unroll
      for (int mi = 0; mi < 2; ++mi)
        af[mi] = frag_ld(As, wm * 32 + mi * 16 + col, kk * 4 + quad);
#pragma unroll
      for (int ni = 0; ni < 4; ++ni)
        bf[ni] = frag_ld(Bs, wn * 64 + ni * 16 + col, kk * 4 + quad);
#pragma unroll
      for (int mi = 0; mi < 2; ++mi)
#pragma unroll
        for (int ni = 0; ni < 4; ++ni)
          acc[mi][ni] = MFMA16(af[mi], bf[ni], acc[mi][ni]);
    }
  }

  float bv[4];
#pragma unroll
  for (int ni = 0; ni < 4; ++ni) bv[ni] = bias[n0 + wn * 64 + ni * 16 + col];

  if (is_final) {
#pragma unroll
    for (int mi = 0; mi < 2; ++mi) {
      const int m_g = m0 + wm * 32 + mi * 16 + quad * 4;
#pragma unroll
      for (int ni = 0; ni < 4; ++ni) {
        const int n_g = n0 + wn * 64 + ni * 16 + col;
#pragma unroll
        for (int r = 0; r < 4; ++r)
          Df[(size_t)(m_g + r) * 1024 + n_g] = acc[mi][ni][r] + bv[ni];
      }
    }
  } else if (z < 2) {
    _Float16* D = z ? Dk : Dq;
#pragma unroll
    for (int mi = 0; mi < 2; ++mi) {
      const int m_g = m0 + wm * 32 + mi * 16 + quad * 4;
#pragma unroll
      for (int ni = 0; ni < 4; ++ni) {
        const int n_g = n0 + wn * 64 + ni * 16 + col;
        const int h = n_g >> 6, dh = n_g & 63;
#pragma unroll
        for (int r = 0; r < 4; ++r) {
          const int b = (m_g + r) >> 10, l = (m_g + r) & 1023;
          D[((size_t)((b * 16 + h) * 1024) + l) * 64 + dh] =
              (_Float16)(acc[mi][ni][r] + bv[ni]);
        }
      }
    }
  } else {
    // transpose 64x128 through LDS -> Vt[bh][dh][l]
    __syncthreads();
    _Float16* Ct = lds;  // [128][72], 72*2B=144B row stride keeps 16B alignment
#pragma unroll
    for (int mi = 0; mi < 2; ++mi) {
      const int ml = wm * 32 + mi * 16 + quad * 4;
#pragma unroll
      for (int ni = 0; ni < 4; ++ni) {
        const int nl = wn * 64 + ni * 16 + col;
#pragma unroll
        for (int r = 0; r < 4; ++r)
          Ct[(size_t)nl * 72 + ml + r] = (_Float16)(acc[mi][ni][r] + bv[ni]);
      }
    }
    __syncthreads();
#pragma unroll
    for (int it = 0; it < 4; ++it) {
      const int ci = it * 256 + tid;
      const int n = ci >> 3;          // 0..127 (dh-global = n0+n)
      const int mc = (ci & 7) * 8;    // l-local chunk
      const half8 hv = *(const half8*)(Ct + (size_t)n * 72 + mc);
      const int n_g = n0 + n;
      const int h = n_g >> 6, dh = n_g & 63;
      const int m_g = m0 + mc;
      const int b = m_g >> 10, l = m_g & 1023;
      *(half8*)(Dvt + ((size_t)((b * 16 + h) * 64 + dh)) * 1024 + l) = hv;
    }
  }
}

// ------------------------------------------------- pipelined flash attention
// grid (LQ/32, B*H), 4 waves: (khalf=wv>>1, qsub=wv&1); 16 q-rows x 512 keys each.
// KV double-buffered (2 x 32KB); bias/mask register-prefetched 1 iter ahead.
// Per-iter vmcnt(16) gate = 8 DMA + 8 bias/mask loads per thread.
__global__ __launch_bounds__(256) void attn(
    const _Float16* __restrict__ Qh, const _Float16* __restrict__ Kh,
    const _Float16* __restrict__ Vt, const float* __restrict__ biasL,
    const int* __restrict__ kpm, _Float16* __restrict__ AO) {
  __shared__ __align__(16) _Float16 KV[2 * 16384];  // [buf][tile: Kh0|Kh1|Vh0|Vh1][4096]
  __shared__ __align__(16) _Float16 Pt[4][1024];    // per-wave P; merge reuses as Ox

  const int tid = threadIdx.x;
  const int wv = tid >> 6, ln = tid & 63;
  const int quad = ln >> 4, col = ln & 15;
  const int qsub = wv & 1, khalf = wv >> 1;
  const int q0 = blockIdx.x * 32;
  const int bh = blockIdx.y;
  const int b = bh >> 4, hh = bh & 15;
  const int qg = q0 + qsub * 16 + col;

  // Q fragments direct from global, fully drained so manual vmcnt counts stay exact
  const _Float16* Qp = Qh + ((size_t)bh * 1024 + qg) * 64;
  const half8 bq0 = *(const half8*)(Qp + quad * 8);
  const half8 bq1 = *(const half8*)(Qp + 32 + quad * 8);
  WAITCNT_VM(0);

  const float* biasRow = biasL + ((size_t)(b * 1024 + qg)) * 1024;
  const int* kpmRow = kpm + b * 1024;
  const int stage_kbase = (wv & 1) * 512;  // tiles 0,2 stage h0; 1,3 stage h1

  // wave wv stages tile-slot wv of buffer buf for key-block `it` (8 DMA issues)
  auto stageKV = [&](int buf, int it) {
    const int skoff = stage_kbase + it * 64;
#pragma unroll
    for (int j = 0; j < 8; ++j) {
      const int ci = j * 64 + ln;
      const int row = ci >> 3;
      const int lc = (ci & 7) ^ (row & 7);
      const void* src =
          (wv < 2) ? (const void*)(Kh + ((size_t)bh * 1024 + skoff + row) * 64 + lc * 8)
                   : (const void*)(Vt + ((size_t)bh * 64 + row) * 1024 + skoff + lc * 8);
      gload16(src, KV + buf * 16384 + wv * 4096 + j * 512);
    }
  };
  auto loadBias = [&](int it, f32x4* bb, int4* mk) {
    const int koff = khalf * 512 + it * 64;
#pragma unroll
    for (int mi = 0; mi < 4; ++mi) {
      const int kg = koff + mi * 16 + quad * 4;
      mk[mi] = *(const int4*)&kpmRow[kg];
      bb[mi] = *(const f32x4*)&biasRow[kg];
    }
  };

  const f32x4 zero4 = {0.f, 0.f, 0.f, 0.f};
  f32x4 o[4];
#pragma unroll
  for (int ni = 0; ni < 4; ++ni) o[ni] = zero4;
  float m_i = -1e30f, l_i = 0.f;
  _Float16* Pw = Pt[wv];

  // one key-block: S^T -> mask/bias -> online softmax -> P roundtrip -> O^T
  auto compute = [&](int buf, const f32x4* bb, const int4* mk) {
    const _Float16* Ks = KV + buf * 16384 + khalf * 4096;
    const _Float16* Vs = KV + buf * 16384 + (2 + khalf) * 4096;
    f32x4 s[4];
#pragma unroll
    for (int mi = 0; mi < 4; ++mi) {
      f32x4 a4 = zero4;
      a4 = MFMA16(frag_ld(Ks, mi * 16 + col, quad), bq0, a4);
      a4 = MFMA16(frag_ld(Ks, mi * 16 + col, 4 + quad), bq1, a4);
      s[mi] = a4;
    }
#pragma unroll
    for (int mi = 0; mi < 4; ++mi) {
      const int* mp = (const int*)&mk[mi];
#pragma unroll
      for (int r = 0; r < 4; ++r)
        s[mi][r] = mp[r] ? -1e9f : s[mi][r] * 0.125f + bb[mi][r];
    }
    float rm = -1e30f;
#pragma unroll
    for (int mi = 0; mi < 4; ++mi)
#pragma unroll
      for (int r = 0; r < 4; ++r) rm = fmaxf(rm, s[mi][r]);
    rm = fmaxf(rm, __shfl_xor(rm, 16));
    rm = fmaxf(rm, __shfl_xor(rm, 32));
    const float mn = fmaxf(m_i, rm);
    const float alpha = __expf(m_i - mn);
    m_i = mn;
    float ps = 0.f;
#pragma unroll
    for (int mi = 0; mi < 4; ++mi)
#pragma unroll
      for (int r = 0; r < 4; ++r) {
        const float p = __expf(s[mi][r] - mn);
        s[mi][r] = p;
        ps += p;
      }
    ps += __shfl_xor(ps, 16);
    ps += __shfl_xor(ps, 32);
    l_i = l_i * alpha + ps;
#pragma unroll
    for (int ni = 0; ni < 4; ++ni)
#pragma unroll
      for (int r = 0; r < 4; ++r) o[ni][r] *= alpha;
#pragma unroll
    for (int mi = 0; mi < 4; ++mi) {
      half4_t h;
      h[0] = (_Float16)s[mi][0]; h[1] = (_Float16)s[mi][1];
      h[2] = (_Float16)s[mi][2]; h[3] = (_Float16)s[mi][3];
      const int kloc = mi * 16 + quad * 4;
      const int chunk = kloc >> 3;
      *(half4_t*)(Pw + col * 64 + (((chunk ^ (col & 7)) << 3) | (kloc & 7))) = h;
    }
    const half8 p0 = frag_ld(Pw, col, quad);
    const half8 p1 = frag_ld(Pw, col, 4 + quad);
#pragma unroll
    for (int ni = 0; ni < 4; ++ni) {
      o[ni] = MFMA16(frag_ld(Vs, ni * 16 + col, quad), p0, o[ni]);
      o[ni] = MFMA16(frag_ld(Vs, ni * 16 + col, 4 + quad), p1, o[ni]);
    }
  };

  f32x4 bbA[4], bbB[4];
  int4 mkA[4], mkB[4];
  stageKV(0, 0);
  loadBias(0, bbA, mkA);
  for (int i = 0; i < 7; ++i) {
    stageKV((i + 1) & 1, i + 1);
    loadBias(i + 1, bbB, mkB);
    WAITCNT_VM(16);  // tile-i DMA + bias-i landed; i+1 (16 ops) in flight
    RAW_BARRIER();
    compute(i & 1, bbA, mkA);
    WAITCNT_LGKM0();
    RAW_BARRIER();   // all waves done reading buf (i&1)
#pragma unroll
    for (int mi = 0; mi < 4; ++mi) { bbA[mi] = bbB[mi]; mkA[mi] = mkB[mi]; }
  }
  WAITCNT_VM(0);
  RAW_BARRIER();
  compute(1, bbA, mkA);  // tile 7, buffer 1

  // split-K merge (khalf 1 -> LDS -> khalf 0), then write AO
  __syncthreads();
  f32x4* Ox = (f32x4*)&Pt[0][0];   // 8KB (P dead)
  float* MlS = (float*)&KV[0];     // 256 floats (KV dead)
  if (khalf == 1) {
#pragma unroll
    for (int ni = 0; ni < 4; ++ni) Ox[(qsub * 4 + ni) * 64 + ln] = o[ni];
    MlS[qsub * 64 + ln] = m_i;
    MlS[128 + qsub * 64 + ln] = l_i;
  }
  __syncthreads();
  if (khalf == 0) {
    const float m2 = MlS[qsub * 64 + ln];
    const float l2 = MlS[128 + qsub * 64 + ln];
    const float ms = fmaxf(m_i, m2);
    const float w1 = __expf(m_i - ms);
    const float w2 = __expf(m2 - ms);
    const float inv = 1.0f / (l_i * w1 + l2 * w2);
#pragma unroll
    for (int ni = 0; ni < 4; ++ni) {
      const f32x4 o2 = Ox[(qsub * 4 + ni) * 64 + ln];
      half4_t h;
#pragma unroll
      for (int r = 0; r < 4; ++r)
        h[r] = (_Float16)((o[ni][r] * w1 + o2[r] * w2) * inv);
      *(half4_t*)&AO[((size_t)(b * 1024 + qg)) * 1024 + hh * 64 + ni * 16 + quad * 4] = h;
    }
  }
}

extern "C" void kernel_launch(void* const* d_in, const int* in_sizes, int n_in,
                              void* d_out, int out_size, void* d_ws, size_t ws_size,
                              hipStream_t stream) {
  (void)in_sizes; (void)n_in; (void)out_size; (void)ws_size;
  const float* q = (const float*)d_in[0];
  const float* k = (const float*)d_in[1];
  const float* v = (const float*)d_in[2];
  const float* Wq = (const float*)d_in[3];
  const float* bq = (const float*)d_in[4];
  const float* Wk = (const float*)d_in[5];
  const float* bk = (const float*)d_in[6];
  const float* Wv = (const float*)d_in[7];
  const float* bv = (const float*)d_in[8];
  const float* Wo = (const float*)d_in[9];
  const float* bo = (const float*)d_in[10];
  const float* lb = (const float*)d_in[11];
  const int* kpm = (const int*)d_in[12];
  float* out = (float*)d_out;

  const size_t NT = (size_t)2 * 1024 * 1024;
  _Float16* q16 = (_Float16*)d_ws;
  _Float16* k16 = q16 + NT;
  _Float16* v16 = k16 + NT;
  _Float16* Qh = v16 + NT;
  _Float16* Kh = Qh + NT;
  _Float16* Vt = Kh + NT;
  _Float16* w16 = Vt + NT;  // 4 x 1M halves (Wq,Wk,Wv,Wo)
  _Float16* AO = q16;       // q16 dead after projections

  cvt_f32_f16<<<dim3(1024, 7), 256, 0, stream>>>(q, k, v, Wq, Wk, Wv, Wo,
                                                 q16, k16, v16, w16);
  mmp<<<dim3(8, 32, 3), 256, 0, stream>>>(q16, k16, v16, w16, bq, bk, bv,
                                          Qh, Kh, Vt, nullptr, 0);
  attn<<<dim3(32, 32), 256, 0, stream>>>(Qh, Kh, Vt, lb, kpm, AO);
  mmp<<<dim3(8, 32, 1), 256, 0, stream>>>(AO, nullptr, nullptr, w16 + 3 * NT / 2,
                                          bo, nullptr, nullptr, nullptr, nullptr,
                                          nullptr, out, 1);
}